// Round 8
// baseline (1824.258 us; speedup 1.0000x reference)
//
#include <hip/hip_runtime.h>
#include <math.h>

// Problem constants (from reference)
#define B_   8
#define T_   128
#define E_   256
#define H_   512
#define G_   2048
#define NWG  256           // 1 WG per CU (146KB LDS), all co-resident (R8-proven)
#define NTHR 512           // 8 waves

typedef unsigned int u32;

// ---------------------------------------------------------------------------
// ALGEBRA (unchanged): softmax sums to 1 over t and h_shared is t-invariant =>
// Rt == h_last; attention path dead. Batches independent -> 8 rings of 32 WGs
// (ring = blockIdx&7, slot = blockIdx>>3 owns h-cols 16s..16s+15).
//
// R16 = R15 + CONGESTION-CONTROLLED POLLING.
// R15 evidence: FETCH 944MB (~7 fabric fetches/thread/step) at 6.3us/step vs
// R8's 73MB at 2.1us/step, with IDENTICAL transport spelling. Only diff: R8's
// serial wave0 finalize (~1us) accidentally throttled pollers (arrive late,
// ~0 retries); R15's fast distributed gates made all 256 WGs spin-hammer the
// MALL at ~800cy period -> request storm -> queueing inflates publish
// visibility to ~5us -> more retries (stable congested equilibrium).
// RULE: the MALL mailbox is latency-stable only below a request-rate knee;
// polling must be PACED. Fix: first poll immediate (common case: data already
// there), then s_sleep(12) (~768cy) between retries (~2.5x request-rate cut).
// Phase C: publish BEFORE out[] store (ring-critical store retires first).
//
// Transport (R8's proven scheme, unchanged from R15):
//  - 4B records, in-band mantissa-LSB parity tag (gen>>1)&1, buffer gen&1.
//  - per-thread poll of OWN float (1x traffic), agent scope (MALL).
//  - publish = ONE 16-lane 64B store by wave0 (one line = one writer; R9/R14
//    violated this and ran 4-6x slower).
// Intra-WG schedule (R15, verified): distributed dot+gates — each wave
// computes its 2 h-cols via kch-split over shared h_lds + 3 shfl_xor + 4 shfl
// gate gather; hOut[16]; barrier; wave0 single-store publish. Fast __expf
// gates. 2 barriers/step.
//
// No-lap (R8 argument): a WG publishes gen g+1 only after its barrier
// confirmed all 512 of gen g validated => everyone read g-1 => 2 buffers
// suffice; parity distinguishes g from g-2. init: buf0 LSB=0, buf1 LSB=1.
// Watchdog: finite poll retries -> wedge = wrong-but-diagnosable, not hang.
//
// LDS = Wl 128K (f32, XOR-swizzle c^((k>>4)&31)) + Xl 16K (bf16, swizzled)
// + h_lds 2K + hOut 64B ~= 146 KiB.
// ---------------------------------------------------------------------------

__device__ __forceinline__ float sigf(float x) {
  return 1.0f / (1.0f + __expf(-x));         // v_exp_f32 path, branchless
}
__device__ __forceinline__ float tanh_f(float x) {
  float xx = fminf(15.0f, fmaxf(-15.0f, x)); // exp(2*15) finite, tanh saturated
  float e  = __expf(2.0f * xx);
  return (e - 1.0f) / (e + 1.0f);
}

__device__ __forceinline__ unsigned short f2bf(float x) {
  u32 u = __float_as_uint(x);
  u += 0x7fffu + ((u >> 16) & 1u);
  return (unsigned short)(u >> 16);
}
__device__ __forceinline__ float bf2f(unsigned short s) {
  return __uint_as_float(((u32)s) << 16);
}

// img: u32[2][8][512] = 32KB at ws start (R8 layout)
__global__ void init_ws(u32* w) {
  int i = blockIdx.x * blockDim.x + threadIdx.x;
  if (i < 4096)      w[i] = 0u;   // buf0: tag 0
  else if (i < 8192) w[i] = 1u;   // buf1: tag 1
}

// LDS index swizzles (used consistently by all readers/writers)
__device__ __forceinline__ int wl_idx(int k, int c) { return k * 64 + (c ^ ((k >> 4) & 31)); }
__device__ __forceinline__ int xl_idx(int c, int t) { return c * T_ + (t ^ ((c & 31) << 1)); }

// Stage k-major slice: Wl[k][c] = W[k][(c>>4)*H + s*16 + (c&15)], k < rows
__device__ __forceinline__ void stage_W(const float* __restrict__ W, int rows,
                                        int s, float* __restrict__ Wl) {
  for (int idx = threadIdx.x; idx < rows * 64; idx += NTHR) {
    int k = idx >> 6, c = idx & 63;
    Wl[wl_idx(k, c)] = W[k * G_ + ((c >> 4) * H_ + s * 16 + (c & 15))];
  }
}

__attribute__((amdgpu_waves_per_eu(2)))
__global__ __launch_bounds__(NTHR, 1) void lstm_all(
    const int* __restrict__ tokens, const float* __restrict__ embed,
    const float* __restrict__ Wih_s, const float* __restrict__ Whh_s,
    const float* __restrict__ b_s,
    const float* __restrict__ Wih_t, const float* __restrict__ Whh_t,
    const float* __restrict__ Wmh_t, const float* __restrict__ b_t,
    float* __restrict__ out, u32* __restrict__ img) {
  __shared__ float Wl[H_ * 64];            // 128 KiB, k-major weight slice (swizzled)
  __shared__ unsigned short Xl[64 * T_];   // 16 KiB, bf16 X (swizzled)
  __shared__ float h_lds[H_];              // 2 KiB, staged h (single buffer, 2-barrier safe)
  __shared__ float hOut[16];               // this slot's 16 new h values

  const int tid = threadIdx.x;
  const int l   = tid & 63;                // lane
  const int wv  = tid >> 6;                // wave: owns h-cols {2wv, 2wv+1} (local)
  const int b   = blockIdx.x & 7;          // ring = batch (guaranteed coverage)
  const int s   = blockIdx.x >> 3;         // slot: h-cols 16s..16s+15
  const int kch = l >> 3;                  // k-chunk 0..7 (64 k each)
  const int cc  = ((l & 7) >> 1) * 16 + 2 * wv + (l & 1);  // this lane's gate col
  const int d   = l & 1;                   // h-col parity within wave
  const int bH  = b * H_;

  int wd = 1 << 20;                        // watchdog: poll retries/thread
  float wreg[64];                          // pinned per-lane weight K-slice

  // ---- X phase: Xl[c][t] (bf16) = emb[b,t] @ Wih[:,col(c)] + bias[col(c)]
  auto computeX = [&](const float* __restrict__ Wih, const float* __restrict__ bias) {
    stage_W(Wih, E_, s, Wl);               // 256x64 into Wl (fits)
    __syncthreads();
    const int t = tid >> 2, grp = tid & 3; // grp = gate; 16 cols each
    const int tok = tokens[b * T_ + t];
    const float4* er = (const float4*)(embed + (size_t)tok * E_);
    float acc[16];
#pragma unroll
    for (int j = 0; j < 16; ++j) acc[j] = bias[grp * H_ + s * 16 + j];
    for (int e4 = 0; e4 < E_ / 4; ++e4) {
      float4 em = er[e4];
#pragma unroll
      for (int eo = 0; eo < 4; ++eo) {
        float ev = reinterpret_cast<const float*>(&em)[eo];
        const int k = e4 * 4 + eo;
#pragma unroll
        for (int j = 0; j < 16; ++j) acc[j] += ev * Wl[wl_idx(k, grp * 16 + j)];
      }
    }
#pragma unroll
    for (int j = 0; j < 16; ++j) Xl[xl_idx(grp * 16 + j, t)] = f2bf(acc[j]);
  };

  auto load_wreg = [&] {
#pragma unroll
    for (int kk = 0; kk < 64; ++kk) wreg[kk] = Wl[wl_idx(kch * 64 + kk, cc)];
#pragma unroll
    for (int kk = 0; kk < 64; ++kk) asm volatile("" : "+v"(wreg[kk]));  // pin
  };

  // Per-THREAD paced poll of OWN float via MALL. First attempt immediate
  // (common case: data arrived during our compute); misses back off ~768cy
  // (s_sleep(12)) to stay below the MALL request-rate knee (R15 lesson).
  auto poll_own = [&](unsigned gen) {
    const u32 par = (gen >> 1) & 1u;
    const u32* p = img + (gen & 1u) * 4096 + bH + tid;
    u32 u = __hip_atomic_load(p, __ATOMIC_RELAXED, __HIP_MEMORY_SCOPE_AGENT);
    while ((u & 1u) != par) {
      if (--wd < 0) break;                 // fail fast, not hang
      __builtin_amdgcn_s_sleep(12);        // paced retry: no fabric storm
      u = __hip_atomic_load(p, __ATOMIC_RELAXED, __HIP_MEMORY_SCOPE_AGENT);
    }
    h_lds[tid] = __uint_as_float(u);       // tag bit kept (1 ulp, harmless)
  };

  // Full dot for this lane's col over shared h_lds: 64 FMAs on its k-chunk
  // (kch-rotated float4 reads: broadcast within 8-lane groups, <=2-way across
  // groups), then 3 shfl_xor over the 8 chunks. (R14/R15-verified math.)
  auto do_dot = [&]() -> float {
    float a0 = 0.f, a1 = 0.f, a2 = 0.f, a3 = 0.f;
    const float4* h4 = (const float4*)(h_lds + kch * 64);
#pragma unroll
    for (int i = 0; i < 16; ++i) {
      const int q = (i + 2 * kch) & 15;    // rotation de-conflicts banks
      float4 hv = h4[q];
      a0 += hv.x * wreg[q * 4 + 0];
      a1 += hv.y * wreg[q * 4 + 1];
      a2 += hv.z * wreg[q * 4 + 2];
      a3 += hv.w * wreg[q * 4 + 3];
    }
    float sum = (a0 + a1) + (a2 + a3);
    sum += __shfl_xor(sum, 8);
    sum += __shfl_xor(sum, 16);
    sum += __shfl_xor(sum, 32);
    return sum;                            // full pre-dot for col cc, all lanes
  };

  // ---------------- Phase A1 + shared weights
  computeX(Wih_s, b_s);
  __syncthreads();
  stage_W(Whh_s, H_, s, Wl);
  __syncthreads();
  load_wreg();

  float c_reg = 0.f, Mreg = 0.f;

  // ---------------- Phase B: shared LSTM; publishes gens 1..128.
  for (int t = 0; t < T_; ++t) {
    float pre = 0.f;
    if (t > 0) {
      poll_own((unsigned)t);
      __syncthreads();                     // barrier 1: h_lds complete
      pre = do_dot();
    }
    if (l < 8) pre += bf2f(Xl[xl_idx(cc, t)]);   // only shfl sources need X
    float gi = __shfl(pre, d),     gf = __shfl(pre, 2 + d),
          gg = __shfl(pre, 4 + d), go = __shfl(pre, 6 + d);
    float cn = sigf(gf) * c_reg + sigf(gi) * tanh_f(gg);
    float hn = sigf(go) * tanh_f(cn);
    c_reg = cn;
    if (l < 2) hOut[2 * wv + l] = hn;      // wave owns h-cols s*16+2wv+{0,1}
    __syncthreads();                       // barrier 2: hOut complete
    if (tid < 16) {                        // SINGLE 16-lane 64B publish (R8 rule)
      const unsigned gw = (unsigned)t + 1u;
      u32 hb = (__float_as_uint(hOut[tid]) & ~1u) | ((gw >> 1) & 1u);
      __hip_atomic_store(img + (gw & 1u) * 4096 + bH + s * 16 + tid, hb,
                         __ATOMIC_RELAXED, __HIP_MEMORY_SCOPE_AGENT);
    }
  }

  // ---------------- M = h_last @ Wmh_t (consume gen 128)
  __syncthreads();
  stage_W(Wmh_t, H_, s, Wl);
  __syncthreads();
  load_wreg();
  poll_own(128u);
  __syncthreads();
  Mreg = do_dot();                         // M for col cc (consistent replicas)

  // ---------------- Phase A2 + task weights
  __syncthreads();
  computeX(Wih_t, b_t);
  __syncthreads();
  stage_W(Whh_t, H_, s, Wl);
  __syncthreads();
  load_wreg();

  // ---------------- Phase C: task LSTM; gens 129..255; out every step
  c_reg = 0.f;
  for (int t = 0; t < T_; ++t) {
    float pre = 0.f;
    if (t > 0) {
      poll_own(128u + (unsigned)t);
      __syncthreads();                     // barrier 1
      pre = do_dot();
    }
    if (l < 8) pre += bf2f(Xl[xl_idx(cc, t)]) + Mreg;
    float gi = __shfl(pre, d),     gf = __shfl(pre, 2 + d),
          gg = __shfl(pre, 4 + d), go = __shfl(pre, 6 + d);
    float cn = sigf(gf) * c_reg + sigf(gi) * tanh_f(gg);
    float hn = sigf(go) * tanh_f(cn);
    c_reg = cn;
    if (l < 2) hOut[2 * wv + l] = hn;
    __syncthreads();                       // barrier 2
    if (tid < 16) {                        // publish FIRST (ring-critical), then out
      if (t < T_ - 1) {
        const unsigned gw = 129u + (unsigned)t;
        u32 hb = (__float_as_uint(hOut[tid]) & ~1u) | ((gw >> 1) & 1u);
        __hip_atomic_store(img + (gw & 1u) * 4096 + bH + s * 16 + tid, hb,
                           __ATOMIC_RELAXED, __HIP_MEMORY_SCOPE_AGENT);
      }
      out[b * (T_ * H_) + t * H_ + s * 16 + tid] = hOut[tid];  // 64B coalesced
    }
  }
}

extern "C" void kernel_launch(void* const* d_in, const int* in_sizes, int n_in,
                              void* d_out, int out_size, void* d_ws, size_t ws_size,
                              hipStream_t stream) {
  const int*   tokens = (const int*)d_in[0];
  // d_in[1] = TASK (unused)
  const float* embed  = (const float*)d_in[2];
  const float* Wih_s  = (const float*)d_in[3];
  const float* Whh_s  = (const float*)d_in[4];
  const float* b_s    = (const float*)d_in[5];
  // d_in[6..9] = Ws_w, Ws_b, Us_w, Us_b -> dead (attention collapses)
  const float* Wih_t  = (const float*)d_in[10];
  const float* Whh_t  = (const float*)d_in[11];
  const float* Wmh_t  = (const float*)d_in[12];
  const float* b_t    = (const float*)d_in[13];
  float* out = (float*)d_out;
  u32*   img = (u32*)d_ws;

  hipLaunchKernelGGL(init_ws, dim3(8), dim3(1024), 0, stream, img);
  hipLaunchKernelGGL(lstm_all, dim3(NWG), dim3(NTHR), 0, stream,
                     tokens, embed, Wih_s, Whh_s, b_s,
                     Wih_t, Whh_t, Wmh_t, b_t, out, img);
}

// Round 9
// 656.535 us; speedup vs baseline: 2.7786x; 2.7786x over previous
//
#include <hip/hip_runtime.h>
#include <math.h>

// Problem constants (from reference)
#define B_   8
#define T_   128
#define E_   256
#define H_   512
#define G_   2048
#define NWG  256           // 1 WG per CU (146KB LDS), all co-resident (R8-proven)
#define NTHR 512           // 8 waves

typedef unsigned int u32;

// ---------------------------------------------------------------------------
// ALGEBRA (unchanged): softmax sums to 1 over t and h_shared is t-invariant =>
// Rt == h_last; attention path dead. Batches independent -> 8 rings of 32 WGs
// (ring = blockIdx&7, slot = blockIdx>>3 owns h-cols 16s..16s+15).
//
// R17 = R16 with THE SCRATCH BUG FIXED.
// Root cause of the R9-R16 4-6x regression vs R8 (found via FETCH+WRITE
// signature: ~900MB fetch + ~140MB write in every slow round, 73MB/8MB in
// R8; R16's 12x retry-pacing change moved NOTHING -> not poll traffic):
//   do_dot indexed the per-lane weight array with a RUNTIME value
//   (wreg[((i+2*kch)&15)*4+j], kch=lane>>3) -> compiler demoted wreg[64] to
//   SCRATCH (rule: runtime-indexed register arrays go to local memory).
//   256B scratch reads/thread/step + spill writes = the entire mystery
//   traffic; VALUBusy 15% = scratch-latency stalls; VGPR 92->124 = shadow
//   copy. R8 was fast because its dot used only compile-time wreg indices.
// Fix: bake the bank-conflict rotation into load_wreg (LDS-side, memory op):
//   wreg[i*4+j] = Wl[wl_idx(kch*64 + q*4 + j, cc)], q=(i+2*kch)&15;
//   do_dot pairs h4[q] (LDS, runtime ok) with wreg[i*4+j] (COMPILE-TIME).
// Same math, same conflict avoidance, no scratch.
//
// Transport (R8's proven scheme): 4B records, in-band mantissa-LSB parity
// tag (gen>>1)&1, buffer gen&1; per-thread poll of OWN float (1x traffic),
// agent scope (MALL), s_sleep(1) retry (R8-proven; pacing theory falsified);
// publish = ONE 16-lane 64B store (one line = one writer).
// Intra-WG schedule (R15/R16, verified): distributed dot+gates — each wave
// computes its 2 h-cols via kch-split + 3 shfl_xor + 4 shfl gate gather;
// hOut[16]; barrier; wave0 single-store publish. Fast __expf gates.
// 2 barriers/step.
//
// No-lap (R8 argument): a WG publishes gen g+1 only after its barrier
// confirmed all 512 of gen g validated => everyone read g-1 => 2 buffers
// suffice; parity distinguishes g from g-2. init: buf0 LSB=0, buf1 LSB=1.
// Watchdog: finite poll retries -> wedge = wrong-but-diagnosable, not hang.
//
// LDS = Wl 128K (f32, XOR-swizzle c^((k>>4)&31)) + Xl 16K (bf16, swizzled)
// + h_lds 2K + hOut 64B ~= 146 KiB.
// ---------------------------------------------------------------------------

__device__ __forceinline__ float sigf(float x) {
  return 1.0f / (1.0f + __expf(-x));         // v_exp_f32 path, branchless
}
__device__ __forceinline__ float tanh_f(float x) {
  float xx = fminf(15.0f, fmaxf(-15.0f, x)); // exp(2*15) finite, tanh saturated
  float e  = __expf(2.0f * xx);
  return (e - 1.0f) / (e + 1.0f);
}

__device__ __forceinline__ unsigned short f2bf(float x) {
  u32 u = __float_as_uint(x);
  u += 0x7fffu + ((u >> 16) & 1u);
  return (unsigned short)(u >> 16);
}
__device__ __forceinline__ float bf2f(unsigned short s) {
  return __uint_as_float(((u32)s) << 16);
}

// img: u32[2][8][512] = 32KB at ws start (R8 layout)
__global__ void init_ws(u32* w) {
  int i = blockIdx.x * blockDim.x + threadIdx.x;
  if (i < 4096)      w[i] = 0u;   // buf0: tag 0
  else if (i < 8192) w[i] = 1u;   // buf1: tag 1
}

// LDS index swizzles (used consistently by all readers/writers)
__device__ __forceinline__ int wl_idx(int k, int c) { return k * 64 + (c ^ ((k >> 4) & 31)); }
__device__ __forceinline__ int xl_idx(int c, int t) { return c * T_ + (t ^ ((c & 31) << 1)); }

// Stage k-major slice: Wl[k][c] = W[k][(c>>4)*H + s*16 + (c&15)], k < rows
__device__ __forceinline__ void stage_W(const float* __restrict__ W, int rows,
                                        int s, float* __restrict__ Wl) {
  for (int idx = threadIdx.x; idx < rows * 64; idx += NTHR) {
    int k = idx >> 6, c = idx & 63;
    Wl[wl_idx(k, c)] = W[k * G_ + ((c >> 4) * H_ + s * 16 + (c & 15))];
  }
}

__attribute__((amdgpu_waves_per_eu(2)))
__global__ __launch_bounds__(NTHR, 1) void lstm_all(
    const int* __restrict__ tokens, const float* __restrict__ embed,
    const float* __restrict__ Wih_s, const float* __restrict__ Whh_s,
    const float* __restrict__ b_s,
    const float* __restrict__ Wih_t, const float* __restrict__ Whh_t,
    const float* __restrict__ Wmh_t, const float* __restrict__ b_t,
    float* __restrict__ out, u32* __restrict__ img) {
  __shared__ float Wl[H_ * 64];            // 128 KiB, k-major weight slice (swizzled)
  __shared__ unsigned short Xl[64 * T_];   // 16 KiB, bf16 X (swizzled)
  __shared__ float h_lds[H_];              // 2 KiB, staged h (single buffer, 2-barrier safe)
  __shared__ float hOut[16];               // this slot's 16 new h values

  const int tid = threadIdx.x;
  const int l   = tid & 63;                // lane
  const int wv  = tid >> 6;                // wave: owns h-cols {2wv, 2wv+1} (local)
  const int b   = blockIdx.x & 7;          // ring = batch (guaranteed coverage)
  const int s   = blockIdx.x >> 3;         // slot: h-cols 16s..16s+15
  const int kch = l >> 3;                  // k-chunk 0..7 (64 k each)
  const int cc  = ((l & 7) >> 1) * 16 + 2 * wv + (l & 1);  // this lane's gate col
  const int d   = l & 1;                   // h-col parity within wave
  const int bH  = b * H_;

  int wd = 1 << 20;                        // watchdog: poll retries/thread
  float wreg[64];                          // pinned per-lane weight K-slice
                                           // (ROTATED storage, see load_wreg)

  // ---- X phase: Xl[c][t] (bf16) = emb[b,t] @ Wih[:,col(c)] + bias[col(c)]
  auto computeX = [&](const float* __restrict__ Wih, const float* __restrict__ bias) {
    stage_W(Wih, E_, s, Wl);               // 256x64 into Wl (fits)
    __syncthreads();
    const int t = tid >> 2, grp = tid & 3; // grp = gate; 16 cols each
    const int tok = tokens[b * T_ + t];
    const float4* er = (const float4*)(embed + (size_t)tok * E_);
    float acc[16];
#pragma unroll
    for (int j = 0; j < 16; ++j) acc[j] = bias[grp * H_ + s * 16 + j];
    for (int e4 = 0; e4 < E_ / 4; ++e4) {
      float4 em = er[e4];
#pragma unroll
      for (int eo = 0; eo < 4; ++eo) {
        float ev = reinterpret_cast<const float*>(&em)[eo];
        const int k = e4 * 4 + eo;
#pragma unroll
        for (int j = 0; j < 16; ++j) acc[j] += ev * Wl[wl_idx(k, grp * 16 + j)];
      }
    }
#pragma unroll
    for (int j = 0; j < 16; ++j) Xl[xl_idx(grp * 16 + j, t)] = f2bf(acc[j]);
  };

  // Load the lane's 64 weights in ROTATED order so do_dot's register indices
  // are all compile-time (scratch-free): slot i holds k-quad q=(i+2*kch)&15.
  auto load_wreg = [&] {
#pragma unroll
    for (int i = 0; i < 16; ++i) {
      const int q = (i + 2 * kch) & 15;    // runtime math feeding an LDS ADDR — ok
#pragma unroll
      for (int j = 0; j < 4; ++j)
        wreg[i * 4 + j] = Wl[wl_idx(kch * 64 + q * 4 + j, cc)];
    }
#pragma unroll
    for (int kk = 0; kk < 64; ++kk) asm volatile("" : "+v"(wreg[kk]));  // pin
  };

  // Per-THREAD poll of OWN float via MALL (R8's proven transport + pacing).
  auto poll_own = [&](unsigned gen) {
    const u32 par = (gen >> 1) & 1u;
    const u32* p = img + (gen & 1u) * 4096 + bH + tid;
    u32 u;
    for (;;) {
      u = __hip_atomic_load(p, __ATOMIC_RELAXED, __HIP_MEMORY_SCOPE_AGENT);
      if ((u & 1u) == par) break;
      if (--wd < 0) break;                 // fail fast, not hang
      __builtin_amdgcn_s_sleep(1);
    }
    h_lds[tid] = __uint_as_float(u);       // tag bit kept (1 ulp, harmless)
  };

  // Full dot for this lane's col over shared h_lds. h4[q]: LDS read, runtime
  // addr fine (kch-rotation de-conflicts banks); wreg[i*4+j]: COMPILE-TIME
  // register index (the R9-R16 scratch bug is here no more).
  auto do_dot = [&]() -> float {
    float a0 = 0.f, a1 = 0.f, a2 = 0.f, a3 = 0.f;
    const float4* h4 = (const float4*)(h_lds + kch * 64);
#pragma unroll
    for (int i = 0; i < 16; ++i) {
      const int q = (i + 2 * kch) & 15;    // matches load_wreg's rotation
      float4 hv = h4[q];
      a0 += hv.x * wreg[i * 4 + 0];
      a1 += hv.y * wreg[i * 4 + 1];
      a2 += hv.z * wreg[i * 4 + 2];
      a3 += hv.w * wreg[i * 4 + 3];
    }
    float sum = (a0 + a1) + (a2 + a3);
    sum += __shfl_xor(sum, 8);
    sum += __shfl_xor(sum, 16);
    sum += __shfl_xor(sum, 32);
    return sum;                            // full pre-dot for col cc, all lanes
  };

  // ---------------- Phase A1 + shared weights
  computeX(Wih_s, b_s);
  __syncthreads();
  stage_W(Whh_s, H_, s, Wl);
  __syncthreads();
  load_wreg();

  float c_reg = 0.f, Mreg = 0.f;

  // ---------------- Phase B: shared LSTM; publishes gens 1..128.
  for (int t = 0; t < T_; ++t) {
    float pre = 0.f;
    if (t > 0) {
      poll_own((unsigned)t);
      __syncthreads();                     // barrier 1: h_lds complete
      pre = do_dot();
    }
    if (l < 8) pre += bf2f(Xl[xl_idx(cc, t)]);   // only shfl sources need X
    float gi = __shfl(pre, d),     gf = __shfl(pre, 2 + d),
          gg = __shfl(pre, 4 + d), go = __shfl(pre, 6 + d);
    float cn = sigf(gf) * c_reg + sigf(gi) * tanh_f(gg);
    float hn = sigf(go) * tanh_f(cn);
    c_reg = cn;
    if (l < 2) hOut[2 * wv + l] = hn;      // wave owns h-cols s*16+2wv+{0,1}
    __syncthreads();                       // barrier 2: hOut complete
    if (tid < 16) {                        // SINGLE 16-lane 64B publish (R8 rule)
      const unsigned gw = (unsigned)t + 1u;
      u32 hb = (__float_as_uint(hOut[tid]) & ~1u) | ((gw >> 1) & 1u);
      __hip_atomic_store(img + (gw & 1u) * 4096 + bH + s * 16 + tid, hb,
                         __ATOMIC_RELAXED, __HIP_MEMORY_SCOPE_AGENT);
    }
  }

  // ---------------- M = h_last @ Wmh_t (consume gen 128)
  __syncthreads();
  stage_W(Wmh_t, H_, s, Wl);
  __syncthreads();
  load_wreg();
  poll_own(128u);
  __syncthreads();
  Mreg = do_dot();                         // M for col cc (consistent replicas)

  // ---------------- Phase A2 + task weights
  __syncthreads();
  computeX(Wih_t, b_t);
  __syncthreads();
  stage_W(Whh_t, H_, s, Wl);
  __syncthreads();
  load_wreg();

  // ---------------- Phase C: task LSTM; gens 129..255; out every step
  c_reg = 0.f;
  for (int t = 0; t < T_; ++t) {
    float pre = 0.f;
    if (t > 0) {
      poll_own(128u + (unsigned)t);
      __syncthreads();                     // barrier 1
      pre = do_dot();
    }
    if (l < 8) pre += bf2f(Xl[xl_idx(cc, t)]) + Mreg;
    float gi = __shfl(pre, d),     gf = __shfl(pre, 2 + d),
          gg = __shfl(pre, 4 + d), go = __shfl(pre, 6 + d);
    float cn = sigf(gf) * c_reg + sigf(gi) * tanh_f(gg);
    float hn = sigf(go) * tanh_f(cn);
    c_reg = cn;
    if (l < 2) hOut[2 * wv + l] = hn;
    __syncthreads();                       // barrier 2
    if (tid < 16) {                        // publish FIRST (ring-critical), then out
      if (t < T_ - 1) {
        const unsigned gw = 129u + (unsigned)t;
        u32 hb = (__float_as_uint(hOut[tid]) & ~1u) | ((gw >> 1) & 1u);
        __hip_atomic_store(img + (gw & 1u) * 4096 + bH + s * 16 + tid, hb,
                           __ATOMIC_RELAXED, __HIP_MEMORY_SCOPE_AGENT);
      }
      out[b * (T_ * H_) + t * H_ + s * 16 + tid] = hOut[tid];  // 64B coalesced
    }
  }
}

extern "C" void kernel_launch(void* const* d_in, const int* in_sizes, int n_in,
                              void* d_out, int out_size, void* d_ws, size_t ws_size,
                              hipStream_t stream) {
  const int*   tokens = (const int*)d_in[0];
  // d_in[1] = TASK (unused)
  const float* embed  = (const float*)d_in[2];
  const float* Wih_s  = (const float*)d_in[3];
  const float* Whh_s  = (const float*)d_in[4];
  const float* b_s    = (const float*)d_in[5];
  // d_in[6..9] = Ws_w, Ws_b, Us_w, Us_b -> dead (attention collapses)
  const float* Wih_t  = (const float*)d_in[10];
  const float* Whh_t  = (const float*)d_in[11];
  const float* Wmh_t  = (const float*)d_in[12];
  const float* b_t    = (const float*)d_in[13];
  float* out = (float*)d_out;
  u32*   img = (u32*)d_ws;

  hipLaunchKernelGGL(init_ws, dim3(8), dim3(1024), 0, stream, img);
  hipLaunchKernelGGL(lstm_all, dim3(NWG), dim3(NTHR), 0, stream,
                     tokens, embed, Wih_s, Whh_s, b_s,
                     Wih_t, Whh_t, Wmh_t, b_t, out, img);
}